// Round 6
// baseline (443.942 us; speedup 1.0000x reference)
//
#include <hip/hip_runtime.h>

typedef _Float16 f16;
typedef f16 half8 __attribute__((ext_vector_type(8)));
typedef float f32x4 __attribute__((ext_vector_type(4)));
typedef unsigned long long u64;
typedef unsigned int u32;
typedef unsigned short u16;

#define KD 8192
#define DIFF_OFF 4194304
#define EIND_OFF 4194305
#define PERP_OFF 4210689
#define LCAP 65536

// ---- ws layout (bytes), total 299016 (< known-safe 331776) ----
// best u64[16384]@0 | Fv@131072 | eev@196608 | idx16 u16[16384]@229376 |
// counts@262144 | dpart f32[1024]@294912 | eemax@299008 | cnt@299012
// ---- d_out scratch (dead before k_out writes quantize) ----
// ehT f16[8192][256]@0 (4MB) | xhT f16[16384][256]@4MB (8MB) |
// m1 u32[16384][32]@12MB (2MB) | m2 u16[16384][32]@14MB (1MB) | list@15MB (256KB)

__device__ inline u32 umin32(u32 a, u32 b) { return a < b ? a : b; }
__device__ inline u32 umax32(u32 a, u32 b) { return a > b ? a : b; }
__device__ inline u64 pack64(float d, unsigned col) {
  u32 u = __float_as_uint(d);
  u = (u >> 31) ? ~u : (u | 0x80000000u);
  return ((u64)u << 32) | col;
}
// exact distance chain — bit-identical to rounds 1-5 (validated absmax 0)
__device__ inline float exact_d(const float* __restrict__ x, const float* __restrict__ e,
                                int b, int hw, int col, float F, const float* __restrict__ eev) {
  float a = 0.f;
#pragma unroll 8
  for (int c = 0; c < 256; ++c)
    a = fmaf(x[((size_t)(b * 256 + c) << 10) + hw], e[(size_t)c * KD + col], a);
  float t = fmaf(-2.f, a, F);
  return t + eev[col];
}

// blocks 0..31: ee | 32..95: Fv | 96..607: ehT | 608..1631: xhT
__global__ __launch_bounds__(256) void k_prep(const float* __restrict__ x,
                                              const float* __restrict__ e,
                                              float* __restrict__ Fv,
                                              float* __restrict__ eev,
                                              u32* __restrict__ eemax,
                                              f16* __restrict__ ehT,
                                              f16* __restrict__ xhT) {
#pragma clang fp contract(off)
  __shared__ float sm[64][65];
  const int bid = blockIdx.x, tid = threadIdx.x;
  if (bid < 32) {              // ||e_k||^2, np sequential order (validated)
    int k = bid * 256 + tid;
    float s = 0.0f;
    for (int c = 0; c < 256; ++c) { float v = e[(size_t)c * KD + k]; float sq = v * v; s = s + sq; }
    eev[k] = s;
    atomicMax(eemax, __float_as_uint(s));
  } else if (bid < 96) {       // ||f_n||^2, numpy pairwise (validated)
    int n = (bid - 32) * 256 + tid;
    int b = n >> 10, hw = n & 1023;
    const float* px = x + ((size_t)b << 18) + hw;
    float sblk[2];
#pragma unroll
    for (int blk = 0; blk < 2; ++blk) {
      float r[8];
#pragma unroll
      for (int j = 0; j < 8; ++j) { float v = px[(size_t)(blk * 128 + j) << 10]; r[j] = v * v; }
      for (int i = 8; i < 128; i += 8) {
#pragma unroll
        for (int j = 0; j < 8; ++j) {
          float v = px[(size_t)(blk * 128 + i + j) << 10];
          float sq = v * v;
          r[j] = r[j] + sq;
        }
      }
      sblk[blk] = ((r[0] + r[1]) + (r[2] + r[3])) + ((r[4] + r[5]) + (r[6] + r[7]));
    }
    Fv[n] = sblk[0] + sblk[1];
  } else if (bid < 608) {      // ehT[k][c] = (f16)e[c][k]
    int t = bid - 96;
    int k0 = (t >> 2) * 64, c0 = (t & 3) * 64;
    int tx = tid & 63, ty = tid >> 6;
#pragma unroll
    for (int i = 0; i < 16; ++i) {
      int cl = i * 4 + ty;
      sm[cl][tx] = e[(size_t)(c0 + cl) * KD + k0 + tx];
    }
    __syncthreads();
#pragma unroll
    for (int i = 0; i < 16; ++i) {
      int kl = i * 4 + ty;
      ehT[(size_t)(k0 + kl) * 256 + c0 + tx] = (f16)sm[tx][kl];
    }
  } else {                     // xhT[n][c] = (f16)x[b][c][hw]  (validated r2)
    int t = bid - 608;
    int b = t >> 6, rem = t & 63;
    int hw0 = (rem >> 2) * 64, c0 = (rem & 3) * 64;
    int tx = tid & 63, ty = tid >> 6;
#pragma unroll
    for (int i = 0; i < 16; ++i) {
      int cl = i * 4 + ty;
      sm[cl][tx] = x[((size_t)(b * 256 + c0 + cl) << 10) + hw0 + tx];
    }
    __syncthreads();
#pragma unroll
    for (int i = 0; i < 16; ++i) {
      int hl = i * 4 + ty;
      xhT[(size_t)(b * 1024 + hw0 + hl) * 256 + c0 + tx] = (f16)sm[tx][hl];
    }
  }
}

// MFMA distance GEMM. Grid 1024 = rowblk(256, 64 rows) x quarter(4, 2048 cols);
// quarter = bid&3 -> stable per XCD (round-robin) -> 1MB ehT slice L2-resident.
// 256 thr = 4 waves (all wn); wave tile 64r x 64c x 8 chunks. A/B frags
// streamed straight from xhT/ehT (b128). 3 waves/SIMD via launch_bounds.
// Keys: d16 = d'+16 > 0 -> raw float bits are ordered; col8 in low mantissa.
__global__ __launch_bounds__(256, 3) void k_gemm(const f16* __restrict__ xhT,
                                                 const f16* __restrict__ ehT,
                                                 const float* __restrict__ eev,
                                                 u32* __restrict__ m1,
                                                 u16* __restrict__ m2) {
  const int tid = threadIdx.x;
  const int lane = tid & 63, wn = tid >> 6;
  const int l15 = lane & 15, g = lane >> 4;
  const int quarter = blockIdx.x & 3;
  const int rowblk = (int)blockIdx.x >> 2;
  const int row0 = rowblk * 64;
  const int colq = quarter * 2048;

  const f16* pa = xhT + (size_t)(row0 + l15) * 256 + g * 8;

  u32 s1[4][4], s2[4][4];
#pragma unroll
  for (int mt = 0; mt < 4; ++mt)
#pragma unroll
    for (int r = 0; r < 4; ++r) { s1[mt][r] = 0xFFFFFFFFu; s2[mt][r] = 0xFFFFFFFFu; }

  for (int chunk = 0; chunk < 8; ++chunk) {
    const int cb = colq + chunk * 256 + wn * 64;
    const f16* pb = ehT + (size_t)(cb + l15) * 256 + g * 8;
    float ee16[4];
#pragma unroll
    for (int nt = 0; nt < 4; ++nt) ee16[nt] = eev[cb + nt * 16 + l15] + 16.0f;

    f32x4 acc[4][4];
#pragma unroll
    for (int i = 0; i < 4; ++i)
#pragma unroll
      for (int j = 0; j < 4; ++j) acc[i][j] = (f32x4){0.f, 0.f, 0.f, 0.f};

#pragma unroll
    for (int kk = 0; kk < 8; ++kk) {
      half8 af[4], bf[4];
#pragma unroll
      for (int mt = 0; mt < 4; ++mt) af[mt] = *(const half8*)(pa + mt * 4096 + kk * 32);
#pragma unroll
      for (int nt = 0; nt < 4; ++nt) bf[nt] = *(const half8*)(pb + nt * 4096 + kk * 32);
#pragma unroll
      for (int mt = 0; mt < 4; ++mt)
#pragma unroll
        for (int nt = 0; nt < 4; ++nt)
          acc[mt][nt] = __builtin_amdgcn_mfma_f32_16x16x32_f16(af[mt], bf[nt], acc[mt][nt], 0, 0, 0);
    }

    // running top-2 (positive-domain keys: 5 VALU/value)
    const u32 i2 = (u32)(chunk & 3);
#pragma unroll
    for (int mt = 0; mt < 4; ++mt) {
#pragma unroll
      for (int r = 0; r < 4; ++r) {
#pragma unroll
        for (int nt = 0; nt < 4; ++nt) {
          float d16 = fmaf(-2.f, acc[mt][nt][r], ee16[nt]);
          u32 k = (__float_as_uint(d16) & 0xFFFFFF00u) | (i2 << 6) | ((u32)nt << 4) | (u32)l15;
          u32 t = umax32(s1[mt][r], k);
          s1[mt][r] = umin32(s1[mt][r], k);
          s2[mt][r] = umin32(s2[mt][r], t);
        }
      }
    }

    if ((chunk & 3) == 3) {   // fold over 16 col-slots, store, reset
      const int cg = chunk >> 2;
      const int sidx = quarter * 8 + wn * 2 + cg;
      const int rr = l15 & 3;
#pragma unroll
      for (int mt = 0; mt < 4; ++mt) {
#pragma unroll
        for (int r = 0; r < 4; ++r) {
#pragma unroll
          for (int msk = 1; msk < 16; msk <<= 1) {
            u32 o1 = (u32)__shfl_xor((int)s1[mt][r], msk, 64);
            u32 o2 = (u32)__shfl_xor((int)s2[mt][r], msk, 64);
            u32 t = umax32(s1[mt][r], o1);
            s1[mt][r] = umin32(s1[mt][r], o1);
            s2[mt][r] = umin32(umin32(s2[mt][r], o2), t);
          }
        }
        u32 v1 = rr == 0 ? s1[mt][0] : rr == 1 ? s1[mt][1] : rr == 2 ? s1[mt][2] : s1[mt][3];
        u32 v2 = rr == 0 ? s2[mt][0] : rr == 1 ? s2[mt][1] : rr == 2 ? s2[mt][2] : s2[mt][3];
        int row = row0 + mt * 16 + g * 4 + rr;
        if (l15 < 4) {
          m1[(size_t)row * 32 + sidx] = v1;
        } else if (l15 < 8) {
          float d2 = __uint_as_float(v2 & 0xFFFFFF00u);   // d16-domain lower bound
          float tq = fmaxf(fminf(d2 * 2048.0f, 65535.f), 0.f);  // NaN-safe order
          m2[(size_t)row * 32 + sidx] = (u16)(u32)tq;
        }
#pragma unroll
        for (int r = 0; r < 4; ++r) { s1[mt][r] = 0xFFFFFFFFu; s2[mt][r] = 0xFFFFFFFFu; }
      }
    }
  }
}

// one wave per row: window test; direct write when unambiguous; else exact
// rescore of in-window sub-top1s + enqueue subs whose top2 is in-window.
__global__ __launch_bounds__(256) void k_sel(const float* __restrict__ x,
                                             const float* __restrict__ e,
                                             const u32* __restrict__ m1,
                                             const u16* __restrict__ m2,
                                             const float* __restrict__ Fv,
                                             const float* __restrict__ eev,
                                             const u32* __restrict__ eemax,
                                             u64* __restrict__ best,
                                             u32* __restrict__ cnt,
                                             u32* __restrict__ list) {
  const int row = blockIdx.x * 4 + (threadIdx.x >> 6);
  const int lane = threadIdx.x & 63;
  u32 m1v = 0xFFFFFFFFu;
  u32 m2v = 0xFFFFu;
  if (lane < 32) {
    m1v = m1[(size_t)row * 32 + lane];
    m2v = (u32)m2[(size_t)row * 32 + lane];
  }
  u32 gk = m1v;
#pragma unroll
  for (int msk = 1; msk < 64; msk <<= 1) gk = umin32(gk, (u32)__shfl_xor((int)gk, msk, 64));
  const float F = Fv[row];
  const float eps = 0x1p-9f * sqrtf(F * __uint_as_float(*eemax)) + 4e-4f;
  const float thr = (__uint_as_float(gk & 0xFFFFFF00u) - 16.0f) + 2.f * eps + 5e-4f;

  const bool f1 = (lane < 32) && (__uint_as_float(m1v & 0xFFFFFF00u) - 16.0f <= thr);
  const bool trig = (lane < 32) && ((float)m2v * (1.0f / 2048.0f) - 16.0f <= thr);
  const u64 bal = __ballot(f1);
  const bool anyt = __any(trig);

  // decode candidate column: sidx = lane = quarter(2)|wn(2)|cg(1)
  const int quarter = lane >> 3, wnn = (lane >> 1) & 3, cg = lane & 1;
  const u32 c8 = m1v & 255u;
  const int col = quarter * 2048 + (cg * 4 + (int)(c8 >> 6)) * 256 + wnn * 64 +
                  (int)((c8 >> 4) & 3u) * 16 + (int)(c8 & 15u);
  const int b = row >> 10, hw = row & 1023;

  if (__popcll(bal) == 1 && !anyt) {
    if (f1) best[row] = (u64)(unsigned)col;        // unambiguous: key 0
  } else {
    if (f1) {
      float d = exact_d(x, e, b, hw, col, F, eev);
      atomicMin(&best[row], pack64(d, (unsigned)col));
    }
    if (trig) {
      u32 slot = atomicAdd(cnt, 1u);
      if (slot < LCAP) list[slot] = (u32)((row << 5) | lane);
      else {   // overflow fallback (correctness only, ~never)
        for (int j = 0; j < 256; ++j) {
          int cj = quarter * 2048 + (cg * 4 + (j >> 6)) * 256 + wnn * 64 + (j & 63);
          float d = exact_d(x, e, b, hw, cj, F, eev);
          atomicMin(&best[row], pack64(d, (unsigned)cj));
        }
      }
    }
  }
}

// full-sub (256-col) exact rescore: wave per task, 4 cols/lane sharing x loads
__global__ __launch_bounds__(256) void k_chunk(const float* __restrict__ x,
                                               const float* __restrict__ e,
                                               const float* __restrict__ Fv,
                                               const float* __restrict__ eev,
                                               const u32* __restrict__ cnt,
                                               const u32* __restrict__ list,
                                               u64* __restrict__ best) {
  u32 n = *cnt; if (n > LCAP) n = LCAP;
  const int lane = threadIdx.x & 63;
  for (u32 t = blockIdx.x * 4 + (threadIdx.x >> 6); t < n; t += gridDim.x * 4) {
    u32 v = list[t];
    int row = (int)(v >> 5), s = (int)(v & 31u);
    int quarter = s >> 3, wnn = (s >> 1) & 3, cg = s & 1;
    int b = row >> 10, hw = row & 1023;
    float F = Fv[row];
    int base = quarter * 2048 + cg * 1024 + wnn * 64 + lane;
    float a0 = 0.f, a1 = 0.f, a2 = 0.f, a3 = 0.f;
#pragma unroll 8
    for (int c = 0; c < 256; ++c) {
      float xv = x[((size_t)(b * 256 + c) << 10) + hw];
      const float* ep = e + (size_t)c * KD + base;
      a0 = fmaf(xv, ep[0], a0);
      a1 = fmaf(xv, ep[256], a1);
      a2 = fmaf(xv, ep[512], a2);
      a3 = fmaf(xv, ep[768], a3);
    }
    float acc4[4] = {a0, a1, a2, a3};
#pragma unroll
    for (int q = 0; q < 4; ++q) {
      int col = base + q * 256;
      float t2 = fmaf(-2.f, acc4[q], F);
      float d = t2 + eev[col];
      atomicMin(&best[row], pack64(d, (unsigned)col));
    }
  }
}

// extract idx (u16) + eind + counts
__global__ __launch_bounds__(256) void k_ind(const u64* __restrict__ best,
                                             u16* __restrict__ idx16,
                                             int* __restrict__ counts,
                                             float* __restrict__ out) {
  int n = blockIdx.x * 256 + threadIdx.x;
  u32 idx = (u32)(best[n] & 0xFFFFFFFFull);
  idx16[n] = (u16)idx;
  out[EIND_OFF + n] = (float)idx;
  atomicAdd(&counts[idx], 1);
}

// quantize + straight-through + diff partials (float4-vectorized)
__global__ __launch_bounds__(256) void k_out(const float* __restrict__ x,
                                             const float* __restrict__ e,
                                             const u16* __restrict__ idx16,
                                             float* __restrict__ out,
                                             float* __restrict__ dpart) {
  __shared__ float sd[256];
  int tid = threadIdx.x;
  float local = 0.0f;
  for (size_t v = (size_t)blockIdx.x * 256 + tid; v < 1048576ull; v += 262144ull) {
    size_t i = v * 4;
    int hw = (int)(i & 1023);
    int c = (int)((i >> 10) & 255);
    int bb = (int)(i >> 18);
    int n = (bb << 10) + hw;
    ushort4 id4 = *(const ushort4*)(idx16 + n);
    float4 xv = *(const float4*)(x + i);
    const float* ec = e + (size_t)c * KD;
    float d0 = ec[id4.x] - xv.x;
    float d1 = ec[id4.y] - xv.y;
    float d2 = ec[id4.z] - xv.z;
    float d3 = ec[id4.w] - xv.w;
    float4 o = {xv.x + d0, xv.y + d1, xv.z + d2, xv.w + d3};
    *(float4*)(out + i) = o;
    local += d0 * d0 + d1 * d1 + d2 * d2 + d3 * d3;
  }
  sd[tid] = local;
  __syncthreads();
  for (int s = 128; s > 0; s >>= 1) {
    if (tid < s) sd[tid] += sd[tid + s];
    __syncthreads();
  }
  if (tid == 0) dpart[blockIdx.x] = sd[0];
}

__global__ __launch_bounds__(256) void k_perp(const int* __restrict__ counts,
                                              const float* __restrict__ dpart,
                                              float* __restrict__ out) {
  __shared__ float sd[256];
  int tid = threadIdx.x;
  float s = 0.0f;
  for (int k = tid; k < KD; k += 256) {
    float p = (float)counts[k] * (1.0f / 16384.0f);
    s += p * logf(p + 1e-10f);
  }
  sd[tid] = s;
  __syncthreads();
  for (int t = 128; t > 0; t >>= 1) {
    if (tid < t) sd[tid] += sd[tid + t];
    __syncthreads();
  }
  float S = sd[0];
  __syncthreads();
  float d = 0.0f;
  for (int t = tid; t < 1024; t += 256) d += dpart[t];
  sd[tid] = d;
  __syncthreads();
  for (int t = 128; t > 0; t >>= 1) {
    if (tid < t) sd[tid] += sd[tid + t];
    __syncthreads();
  }
  if (tid == 0) {
    out[DIFF_OFF] = sd[0] * (1.0f / 4194304.0f);
    out[PERP_OFF] = expf(-S);
  }
}

extern "C" void kernel_launch(void* const* d_in, const int* in_sizes, int n_in,
                              void* d_out, int out_size, void* d_ws, size_t ws_size,
                              hipStream_t stream) {
  const float* x = (const float*)d_in[0];   // [16,256,32,32]
  const float* e = (const float*)d_in[1];   // [256,8192]
  float* out = (float*)d_out;
  char* dc = (char*)d_out;
  char* ws = (char*)d_ws;

  u64* best = (u64*)(ws);
  float* Fv = (float*)(ws + 131072);
  float* eev = (float*)(ws + 196608);
  u16* idx16 = (u16*)(ws + 229376);
  int* counts = (int*)(ws + 262144);
  float* dpart = (float*)(ws + 294912);
  u32* eemax = (u32*)(ws + 299008);
  u32* cnt = (u32*)(ws + 299012);

  f16* ehT = (f16*)(dc);
  f16* xhT = (f16*)(dc + 4194304);
  u32* m1 = (u32*)(dc + 12582912);
  u16* m2 = (u16*)(dc + 14680064);
  u32* list = (u32*)(dc + 15728640);

  hipMemsetAsync(best, 0xFF, 131072, stream);
  hipMemsetAsync(counts, 0, 36872, stream);   // counts+dpart+eemax+cnt

  k_prep<<<1632, 256, 0, stream>>>(x, e, Fv, eev, eemax, ehT, xhT);
  k_gemm<<<1024, 256, 0, stream>>>(xhT, ehT, eev, m1, m2);
  k_sel<<<4096, 256, 0, stream>>>(x, e, m1, m2, Fv, eev, eemax, best, cnt, list);
  k_chunk<<<1024, 256, 0, stream>>>(x, e, Fv, eev, cnt, list, best);
  k_ind<<<64, 256, 0, stream>>>(best, idx16, counts, out);
  k_out<<<1024, 256, 0, stream>>>(x, e, idx16, out, dpart);
  k_perp<<<1, 256, 0, stream>>>(counts, dpart, out);
}

// Round 7
// 392.981 us; speedup vs baseline: 1.1297x; 1.1297x over previous
//
#include <hip/hip_runtime.h>

typedef _Float16 f16;
typedef f16 half8 __attribute__((ext_vector_type(8)));
typedef float f32x4 __attribute__((ext_vector_type(4)));
typedef unsigned long long u64;
typedef unsigned int u32;
typedef unsigned short u16;

#define KD 8192
#define DIFF_OFF 4194304
#define EIND_OFF 4194305
#define PERP_OFF 4210689
#define LCAP 65536

// ---- ws layout (bytes), total 299016 (< known-safe 331776) ----
// best u64[16384]@0 | Fv@131072 | eev@196608 | idx16 u16[16384]@229376 |
// counts@262144 | dpart f32[1024]@294912 | eemax@299008 | cnt@299012
// ---- d_out scratch (dead before k_out writes quantize) ----
// ehT f16[8192][256]@0 (4MB) | xhT f16[16384][256]@4MB (8MB) |
// m1 u32[16384][32]@12MB (2MB) | m2 u16[16384][32]@14MB (1MB) | list@15MB (256KB)

__device__ inline u32 umin32(u32 a, u32 b) { return a < b ? a : b; }
__device__ inline u32 umax32(u32 a, u32 b) { return a > b ? a : b; }
__device__ inline u64 pack64(float d, unsigned col) {
  u32 u = __float_as_uint(d);
  u = (u >> 31) ? ~u : (u | 0x80000000u);
  return ((u64)u << 32) | col;
}
// exact distance chain — bit-identical to rounds 1-6 (validated absmax 0)
__device__ inline float exact_d(const float* __restrict__ x, const float* __restrict__ e,
                                int b, int hw, int col, float F, const float* __restrict__ eev) {
  float a = 0.f;
#pragma unroll 8
  for (int c = 0; c < 256; ++c)
    a = fmaf(x[((size_t)(b * 256 + c) << 10) + hw], e[(size_t)c * KD + col], a);
  float t = fmaf(-2.f, a, F);
  return t + eev[col];
}

// blocks 0..31: ee | 32..95: Fv | 96..607: ehT | 608..1631: xhT
__global__ __launch_bounds__(256) void k_prep(const float* __restrict__ x,
                                              const float* __restrict__ e,
                                              float* __restrict__ Fv,
                                              float* __restrict__ eev,
                                              u32* __restrict__ eemax,
                                              f16* __restrict__ ehT,
                                              f16* __restrict__ xhT) {
#pragma clang fp contract(off)
  __shared__ float sm[64][65];
  const int bid = blockIdx.x, tid = threadIdx.x;
  if (bid < 32) {              // ||e_k||^2, np sequential order (validated)
    int k = bid * 256 + tid;
    float s = 0.0f;
    for (int c = 0; c < 256; ++c) { float v = e[(size_t)c * KD + k]; float sq = v * v; s = s + sq; }
    eev[k] = s;
    atomicMax(eemax, __float_as_uint(s));
  } else if (bid < 96) {       // ||f_n||^2, numpy pairwise (validated)
    int n = (bid - 32) * 256 + tid;
    int b = n >> 10, hw = n & 1023;
    const float* px = x + ((size_t)b << 18) + hw;
    float sblk[2];
#pragma unroll
    for (int blk = 0; blk < 2; ++blk) {
      float r[8];
#pragma unroll
      for (int j = 0; j < 8; ++j) { float v = px[(size_t)(blk * 128 + j) << 10]; r[j] = v * v; }
      for (int i = 8; i < 128; i += 8) {
#pragma unroll
        for (int j = 0; j < 8; ++j) {
          float v = px[(size_t)(blk * 128 + i + j) << 10];
          float sq = v * v;
          r[j] = r[j] + sq;
        }
      }
      sblk[blk] = ((r[0] + r[1]) + (r[2] + r[3])) + ((r[4] + r[5]) + (r[6] + r[7]));
    }
    Fv[n] = sblk[0] + sblk[1];
  } else if (bid < 608) {      // ehT[k][c] = (f16)e[c][k]
    int t = bid - 96;
    int k0 = (t >> 2) * 64, c0 = (t & 3) * 64;
    int tx = tid & 63, ty = tid >> 6;
#pragma unroll
    for (int i = 0; i < 16; ++i) {
      int cl = i * 4 + ty;
      sm[cl][tx] = e[(size_t)(c0 + cl) * KD + k0 + tx];
    }
    __syncthreads();
#pragma unroll
    for (int i = 0; i < 16; ++i) {
      int kl = i * 4 + ty;
      ehT[(size_t)(k0 + kl) * 256 + c0 + tx] = (f16)sm[tx][kl];
    }
  } else {                     // xhT[n][c] = (f16)x[b][c][hw]  (validated r2)
    int t = bid - 608;
    int b = t >> 6, rem = t & 63;
    int hw0 = (rem >> 2) * 64, c0 = (rem & 3) * 64;
    int tx = tid & 63, ty = tid >> 6;
#pragma unroll
    for (int i = 0; i < 16; ++i) {
      int cl = i * 4 + ty;
      sm[cl][tx] = x[((size_t)(b * 256 + c0 + cl) << 10) + hw0 + tx];
    }
    __syncthreads();
#pragma unroll
    for (int i = 0; i < 16; ++i) {
      int hl = i * 4 + ty;
      xhT[(size_t)(b * 1024 + hw0 + hl) * 256 + c0 + tx] = (f16)sm[tx][hl];
    }
  }
}

// MFMA distance GEMM. Grid 2048 = rowblk(256, 64 rows) x eighth(8, 1024 cols).
// Any WG->XCD mix keeps B L2-resident (8 x 512KB = 4MB = L2). 8 waves 2x4;
// wave-tile 32r x 256c over 4 chunks of 64c. A register-resident from xhT
// (b128, loaded once). B ping-pong prefetch. Keys: d16 = d'+16 > 0 so raw
// float bits are ordered; col8 in low mantissa. Single fold+store at end.
__global__ __launch_bounds__(512, 3) void k_gemm(const f16* __restrict__ xhT,
                                                 const f16* __restrict__ ehT,
                                                 const float* __restrict__ eev,
                                                 u32* __restrict__ m1,
                                                 u16* __restrict__ m2) {
  const int tid = threadIdx.x;
  const int lane = tid & 63, w = tid >> 6;
  const int wm = w >> 2, wn = w & 3;
  const int l15 = lane & 15, g = lane >> 4;
  const int eighth = blockIdx.x & 7;
  const int rowblk = (int)blockIdx.x >> 3;
  const int row0 = rowblk * 64;
  const int colE = eighth * 1024;

  // A resident: af[mt][kk] = 64 VGPRs, single pass from xhT
  half8 af[2][8];
#pragma unroll
  for (int mt = 0; mt < 2; ++mt) {
    const f16* pa = xhT + (size_t)(row0 + wm * 32 + mt * 16 + l15) * 256 + g * 8;
#pragma unroll
    for (int kk = 0; kk < 8; ++kk) af[mt][kk] = *(const half8*)(pa + kk * 32);
  }

  u32 s1[2][4], s2[2][4];
#pragma unroll
  for (int mt = 0; mt < 2; ++mt)
#pragma unroll
    for (int r = 0; r < 4; ++r) { s1[mt][r] = 0xFFFFFFFFu; s2[mt][r] = 0xFFFFFFFFu; }

  for (int chunk = 0; chunk < 4; ++chunk) {
    const int cb = colE + chunk * 256 + wn * 64;
    const f16* pb = ehT + (size_t)(cb + l15) * 256 + g * 8;
    float ee16[4];
#pragma unroll
    for (int nt = 0; nt < 4; ++nt) ee16[nt] = eev[cb + nt * 16 + l15] + 16.0f;

    f32x4 acc[2][4];
#pragma unroll
    for (int i = 0; i < 2; ++i)
#pragma unroll
      for (int j = 0; j < 4; ++j) acc[i][j] = (f32x4){0.f, 0.f, 0.f, 0.f};

    half8 bf[2][4];
#pragma unroll
    for (int nt = 0; nt < 4; ++nt) bf[0][nt] = *(const half8*)(pb + nt * 4096);
#pragma unroll
    for (int kk = 0; kk < 8; ++kk) {
      if (kk < 7) {
#pragma unroll
        for (int nt = 0; nt < 4; ++nt)
          bf[(kk + 1) & 1][nt] = *(const half8*)(pb + nt * 4096 + (kk + 1) * 32);
      }
#pragma unroll
      for (int mt = 0; mt < 2; ++mt)
#pragma unroll
        for (int nt = 0; nt < 4; ++nt)
          acc[mt][nt] = __builtin_amdgcn_mfma_f32_16x16x32_f16(af[mt][kk], bf[kk & 1][nt], acc[mt][nt], 0, 0, 0);
    }

    // running top-2 (positive-domain keys: 5 VALU/value)
    const u32 i2 = (u32)chunk;
#pragma unroll
    for (int mt = 0; mt < 2; ++mt) {
#pragma unroll
      for (int r = 0; r < 4; ++r) {
#pragma unroll
        for (int nt = 0; nt < 4; ++nt) {
          float d16 = fmaf(-2.f, acc[mt][nt][r], ee16[nt]);
          u32 k = (__float_as_uint(d16) & 0xFFFFFF00u) | (i2 << 6) | ((u32)nt << 4) | (u32)l15;
          u32 t = umax32(s1[mt][r], k);
          s1[mt][r] = umin32(s1[mt][r], k);
          s2[mt][r] = umin32(s2[mt][r], t);
        }
      }
    }
  }

  // single fold over 16 col-slots + store
  const int sidx = eighth * 4 + wn;
  const int rr = l15 & 3;
#pragma unroll
  for (int mt = 0; mt < 2; ++mt) {
#pragma unroll
    for (int r = 0; r < 4; ++r) {
#pragma unroll
      for (int msk = 1; msk < 16; msk <<= 1) {
        u32 o1 = (u32)__shfl_xor((int)s1[mt][r], msk, 64);
        u32 o2 = (u32)__shfl_xor((int)s2[mt][r], msk, 64);
        u32 t = umax32(s1[mt][r], o1);
        s1[mt][r] = umin32(s1[mt][r], o1);
        s2[mt][r] = umin32(umin32(s2[mt][r], o2), t);
      }
    }
    u32 v1 = rr == 0 ? s1[mt][0] : rr == 1 ? s1[mt][1] : rr == 2 ? s1[mt][2] : s1[mt][3];
    u32 v2 = rr == 0 ? s2[mt][0] : rr == 1 ? s2[mt][1] : rr == 2 ? s2[mt][2] : s2[mt][3];
    int row = row0 + wm * 32 + mt * 16 + g * 4 + rr;
    if (l15 < 4) {
      m1[(size_t)row * 32 + sidx] = v1;
    } else if (l15 < 8) {
      float d2 = __uint_as_float(v2 & 0xFFFFFF00u);        // d16-domain lower bound
      float tq = fmaxf(fminf(d2 * 2048.0f, 65535.f), 0.f);
      m2[(size_t)row * 32 + sidx] = (u16)(u32)tq;
    }
  }
}

// one wave per row: window test; direct write when unambiguous; else exact
// rescore of in-window sub-top1s + enqueue subs whose top2 is in-window.
__global__ __launch_bounds__(256) void k_sel(const float* __restrict__ x,
                                             const float* __restrict__ e,
                                             const u32* __restrict__ m1,
                                             const u16* __restrict__ m2,
                                             const float* __restrict__ Fv,
                                             const float* __restrict__ eev,
                                             const u32* __restrict__ eemax,
                                             u64* __restrict__ best,
                                             u32* __restrict__ cnt,
                                             u32* __restrict__ list) {
  const int row = blockIdx.x * 4 + (threadIdx.x >> 6);
  const int lane = threadIdx.x & 63;
  u32 m1v = 0xFFFFFFFFu;
  u32 m2v = 0xFFFFu;
  if (lane < 32) {
    m1v = m1[(size_t)row * 32 + lane];
    m2v = (u32)m2[(size_t)row * 32 + lane];
  }
  u32 gk = m1v;
#pragma unroll
  for (int msk = 1; msk < 64; msk <<= 1) gk = umin32(gk, (u32)__shfl_xor((int)gk, msk, 64));
  const float F = Fv[row];
  const float eps = 0x1p-9f * sqrtf(F * __uint_as_float(*eemax)) + 4e-4f;
  const float thr = (__uint_as_float(gk & 0xFFFFFF00u) - 16.0f) + 2.f * eps + 5e-4f;

  const bool f1 = (lane < 32) && (__uint_as_float(m1v & 0xFFFFFF00u) - 16.0f <= thr);
  const bool trig = (lane < 32) && ((float)m2v * (1.0f / 2048.0f) - 16.0f <= thr);
  const u64 bal = __ballot(f1);
  const bool anyt = __any(trig);

  // decode candidate column: sidx = lane = eighth(3b)|wn(2b)
  const int eighth = lane >> 2, wnn = lane & 3;
  const u32 c8 = m1v & 255u;
  const int col = eighth * 1024 + (int)(c8 >> 6) * 256 + wnn * 64 +
                  (int)((c8 >> 4) & 3u) * 16 + (int)(c8 & 15u);
  const int b = row >> 10, hw = row & 1023;

  if (__popcll(bal) == 1 && !anyt) {
    if (f1) best[row] = (u64)(unsigned)col;        // unambiguous: key 0
  } else {
    if (f1) {
      float d = exact_d(x, e, b, hw, col, F, eev);
      atomicMin(&best[row], pack64(d, (unsigned)col));
    }
    if (trig) {
      u32 slot = atomicAdd(cnt, 1u);
      if (slot < LCAP) list[slot] = (u32)((row << 5) | lane);
      else {   // overflow fallback (correctness only, ~never)
        for (int j = 0; j < 256; ++j) {
          int cj = eighth * 1024 + (j >> 6) * 256 + wnn * 64 + (j & 63);
          float d = exact_d(x, e, b, hw, cj, F, eev);
          atomicMin(&best[row], pack64(d, (unsigned)cj));
        }
      }
    }
  }
}

// full-sub (256-col) exact rescore: wave per task, 4 cols/lane sharing x loads
__global__ __launch_bounds__(256) void k_chunk(const float* __restrict__ x,
                                               const float* __restrict__ e,
                                               const float* __restrict__ Fv,
                                               const float* __restrict__ eev,
                                               const u32* __restrict__ cnt,
                                               const u32* __restrict__ list,
                                               u64* __restrict__ best) {
  u32 n = *cnt; if (n > LCAP) n = LCAP;
  const int lane = threadIdx.x & 63;
  for (u32 t = blockIdx.x * 4 + (threadIdx.x >> 6); t < n; t += gridDim.x * 4) {
    u32 v = list[t];
    int row = (int)(v >> 5), s = (int)(v & 31u);
    int eighth = s >> 2, wnn = s & 3;
    int b = row >> 10, hw = row & 1023;
    float F = Fv[row];
    int base = eighth * 1024 + wnn * 64 + lane;
    float a0 = 0.f, a1 = 0.f, a2 = 0.f, a3 = 0.f;
#pragma unroll 8
    for (int c = 0; c < 256; ++c) {
      float xv = x[((size_t)(b * 256 + c) << 10) + hw];
      const float* ep = e + (size_t)c * KD + base;
      a0 = fmaf(xv, ep[0], a0);
      a1 = fmaf(xv, ep[256], a1);
      a2 = fmaf(xv, ep[512], a2);
      a3 = fmaf(xv, ep[768], a3);
    }
    float acc4[4] = {a0, a1, a2, a3};
#pragma unroll
    for (int q = 0; q < 4; ++q) {
      int col = base + q * 256;
      float t2 = fmaf(-2.f, acc4[q], F);
      float d = t2 + eev[col];
      atomicMin(&best[row], pack64(d, (unsigned)col));
    }
  }
}

// extract idx (u16) + eind + counts
__global__ __launch_bounds__(256) void k_ind(const u64* __restrict__ best,
                                             u16* __restrict__ idx16,
                                             int* __restrict__ counts,
                                             float* __restrict__ out) {
  int n = blockIdx.x * 256 + threadIdx.x;
  u32 idx = (u32)(best[n] & 0xFFFFFFFFull);
  idx16[n] = (u16)idx;
  out[EIND_OFF + n] = (float)idx;
  atomicAdd(&counts[idx], 1);
}

// quantize + straight-through + diff partials (float4-vectorized)
__global__ __launch_bounds__(256) void k_out(const float* __restrict__ x,
                                             const float* __restrict__ e,
                                             const u16* __restrict__ idx16,
                                             float* __restrict__ out,
                                             float* __restrict__ dpart) {
  __shared__ float sd[256];
  int tid = threadIdx.x;
  float local = 0.0f;
  for (size_t v = (size_t)blockIdx.x * 256 + tid; v < 1048576ull; v += 262144ull) {
    size_t i = v * 4;
    int hw = (int)(i & 1023);
    int c = (int)((i >> 10) & 255);
    int bb = (int)(i >> 18);
    int n = (bb << 10) + hw;
    ushort4 id4 = *(const ushort4*)(idx16 + n);
    float4 xv = *(const float4*)(x + i);
    const float* ec = e + (size_t)c * KD;
    float d0 = ec[id4.x] - xv.x;
    float d1 = ec[id4.y] - xv.y;
    float d2 = ec[id4.z] - xv.z;
    float d3 = ec[id4.w] - xv.w;
    float4 o = {xv.x + d0, xv.y + d1, xv.z + d2, xv.w + d3};
    *(float4*)(out + i) = o;
    local += d0 * d0 + d1 * d1 + d2 * d2 + d3 * d3;
  }
  sd[tid] = local;
  __syncthreads();
  for (int s = 128; s > 0; s >>= 1) {
    if (tid < s) sd[tid] += sd[tid + s];
    __syncthreads();
  }
  if (tid == 0) dpart[blockIdx.x] = sd[0];
}

__global__ __launch_bounds__(256) void k_perp(const int* __restrict__ counts,
                                              const float* __restrict__ dpart,
                                              float* __restrict__ out) {
  __shared__ float sd[256];
  int tid = threadIdx.x;
  float s = 0.0f;
  for (int k = tid; k < KD; k += 256) {
    float p = (float)counts[k] * (1.0f / 16384.0f);
    s += p * logf(p + 1e-10f);
  }
  sd[tid] = s;
  __syncthreads();
  for (int t = 128; t > 0; t >>= 1) {
    if (tid < t) sd[tid] += sd[tid + t];
    __syncthreads();
  }
  float S = sd[0];
  __syncthreads();
  float d = 0.0f;
  for (int t = tid; t < 1024; t += 256) d += dpart[t];
  sd[tid] = d;
  __syncthreads();
  for (int t = 128; t > 0; t >>= 1) {
    if (tid < t) sd[tid] += sd[tid + t];
    __syncthreads();
  }
  if (tid == 0) {
    out[DIFF_OFF] = sd[0] * (1.0f / 4194304.0f);
    out[PERP_OFF] = expf(-S);
  }
}

extern "C" void kernel_launch(void* const* d_in, const int* in_sizes, int n_in,
                              void* d_out, int out_size, void* d_ws, size_t ws_size,
                              hipStream_t stream) {
  const float* x = (const float*)d_in[0];   // [16,256,32,32]
  const float* e = (const float*)d_in[1];   // [256,8192]
  float* out = (float*)d_out;
  char* dc = (char*)d_out;
  char* ws = (char*)d_ws;

  u64* best = (u64*)(ws);
  float* Fv = (float*)(ws + 131072);
  float* eev = (float*)(ws + 196608);
  u16* idx16 = (u16*)(ws + 229376);
  int* counts = (int*)(ws + 262144);
  float* dpart = (float*)(ws + 294912);
  u32* eemax = (u32*)(ws + 299008);
  u32* cnt = (u32*)(ws + 299012);

  f16* ehT = (f16*)(dc);
  f16* xhT = (f16*)(dc + 4194304);
  u32* m1 = (u32*)(dc + 12582912);
  u16* m2 = (u16*)(dc + 14680064);
  u32* list = (u32*)(dc + 15728640);

  hipMemsetAsync(best, 0xFF, 131072, stream);
  hipMemsetAsync(counts, 0, 36872, stream);   // counts+dpart+eemax+cnt

  k_prep<<<1632, 256, 0, stream>>>(x, e, Fv, eev, eemax, ehT, xhT);
  k_gemm<<<2048, 512, 0, stream>>>(xhT, ehT, eev, m1, m2);
  k_sel<<<4096, 256, 0, stream>>>(x, e, m1, m2, Fv, eev, eemax, best, cnt, list);
  k_chunk<<<1024, 256, 0, stream>>>(x, e, Fv, eev, cnt, list, best);
  k_ind<<<64, 256, 0, stream>>>(best, idx16, counts, out);
  k_out<<<1024, 256, 0, stream>>>(x, e, idx16, out, dpart);
  k_perp<<<1, 256, 0, stream>>>(counts, dpart, out);
}

// Round 8
// 322.486 us; speedup vs baseline: 1.3766x; 1.2186x over previous
//
#include <hip/hip_runtime.h>

typedef _Float16 f16;
typedef f16 half8 __attribute__((ext_vector_type(8)));
typedef float f32x4 __attribute__((ext_vector_type(4)));
typedef unsigned long long u64;
typedef unsigned int u32;
typedef unsigned short u16;

#define KD 8192
#define DIFF_OFF 4194304
#define EIND_OFF 4194305
#define PERP_OFF 4210689
#define LCAP 262144

// ---- ws layout (bytes), total 299016 (< known-safe 331776) ----
// best u64[16384]@0 | Fv@131072 | eev@196608 | idx16 u16[16384]@229376 |
// counts@262144 | dpart f32[1024]@294912 | eemax@299008 | cnt@299012
// ---- d_out scratch (dead before k_out writes quantize) ----
// ehTf f16 frag-linear [512 tiles][8 kk][64 lane][8] @0      (4MB)
// xhTf f16 frag-linear [1024 tiles][8][64][8]        @4MB    (8MB)
// m1 u32[16384][16] @12582912 (1MB) | m2 u16[16384][16] @13631488 (512KB)
// list u32[LCAP] @14155776 (1MB)

__device__ inline u32 umin32(u32 a, u32 b) { return a < b ? a : b; }
__device__ inline u32 umax32(u32 a, u32 b) { return a > b ? a : b; }
__device__ inline u64 pack64(float d, unsigned col) {
  u32 u = __float_as_uint(d);
  u = (u >> 31) ? ~u : (u | 0x80000000u);
  return ((u64)u << 32) | col;
}
// exact distance chain — bit-identical to rounds 1-7 (validated absmax 0)
__device__ inline float exact_d(const float* __restrict__ x, const float* __restrict__ e,
                                int b, int hw, int col, float F, const float* __restrict__ eev) {
  float a = 0.f;
#pragma unroll 8
  for (int c = 0; c < 256; ++c)
    a = fmaf(x[((size_t)(b * 256 + c) << 10) + hw], e[(size_t)c * KD + col], a);
  float t = fmaf(-2.f, a, F);
  return t + eev[col];
}

// blocks 0..31: ee | 32..95: Fv | 96..607: ehTf | 608..1631: xhTf
__global__ __launch_bounds__(256) void k_prep(const float* __restrict__ x,
                                              const float* __restrict__ e,
                                              float* __restrict__ Fv,
                                              float* __restrict__ eev,
                                              u32* __restrict__ eemax,
                                              f16* __restrict__ ehTf,
                                              f16* __restrict__ xhTf) {
#pragma clang fp contract(off)
  __shared__ float sm[64][65];
  const int bid = blockIdx.x, tid = threadIdx.x;
  if (bid < 32) {              // ||e_k||^2, np sequential order (validated)
    int k = bid * 256 + tid;
    float s = 0.0f;
    for (int c = 0; c < 256; ++c) { float v = e[(size_t)c * KD + k]; float sq = v * v; s = s + sq; }
    eev[k] = s;
    atomicMax(eemax, __float_as_uint(s));
  } else if (bid < 96) {       // ||f_n||^2, numpy pairwise (validated)
    int n = (bid - 32) * 256 + tid;
    int b = n >> 10, hw = n & 1023;
    const float* px = x + ((size_t)b << 18) + hw;
    float sblk[2];
#pragma unroll
    for (int blk = 0; blk < 2; ++blk) {
      float r[8];
#pragma unroll
      for (int j = 0; j < 8; ++j) { float v = px[(size_t)(blk * 128 + j) << 10]; r[j] = v * v; }
      for (int i = 8; i < 128; i += 8) {
#pragma unroll
        for (int j = 0; j < 8; ++j) {
          float v = px[(size_t)(blk * 128 + i + j) << 10];
          float sq = v * v;
          r[j] = r[j] + sq;
        }
      }
      sblk[blk] = ((r[0] + r[1]) + (r[2] + r[3])) + ((r[4] + r[5]) + (r[6] + r[7]));
    }
    Fv[n] = sblk[0] + sblk[1];
  } else if (bid < 608) {      // ehTf fragment-linear from e[c][k]
    int t = bid - 96;
    int k0 = (t >> 2) * 64, c0 = (t & 3) * 64;
    int tx = tid & 63, ty = tid >> 6;
#pragma unroll
    for (int i = 0; i < 16; ++i) {
      int cl = i * 4 + ty;
      sm[cl][tx] = e[(size_t)(c0 + cl) * KD + k0 + tx];
    }
    __syncthreads();
#pragma unroll
    for (int p = 0; p < 2; ++p) {
      int i = tid + p * 256;
      int kl = i & 63, cg = i >> 6;
      int kkl = cg >> 2, gg = cg & 3;
      int chb = kkl * 32 + gg * 8;
      half8 h;
#pragma unroll
      for (int j = 0; j < 8; ++j) h[j] = (f16)sm[chb + j][kl];
      int tile = (k0 >> 4) + (kl >> 4);
      int kk = (c0 >> 5) + kkl;
      int lanef = gg * 16 + (kl & 15);
      *(half8*)(ehTf + ((size_t)(tile * 8 + kk) * 64 + lanef) * 8) = h;
    }
  } else {                     // xhTf fragment-linear from x[b][c][hw]
    int t = bid - 608;
    int b = t >> 6, rem = t & 63;
    int hw0 = (rem >> 2) * 64, c0 = (rem & 3) * 64;
    int tx = tid & 63, ty = tid >> 6;
#pragma unroll
    for (int i = 0; i < 16; ++i) {
      int cl = i * 4 + ty;
      sm[cl][tx] = x[((size_t)(b * 256 + c0 + cl) << 10) + hw0 + tx];
    }
    __syncthreads();
#pragma unroll
    for (int p = 0; p < 2; ++p) {
      int i = tid + p * 256;
      int nl = i & 63, cg = i >> 6;
      int kkl = cg >> 2, gg = cg & 3;
      int chb = kkl * 32 + gg * 8;
      half8 h;
#pragma unroll
      for (int j = 0; j < 8; ++j) h[j] = (f16)sm[chb + j][nl];
      int rt = b * 64 + (hw0 >> 4) + (nl >> 4);
      int kk = (c0 >> 5) + kkl;
      int lanef = gg * 16 + (nl & 15);
      *(half8*)(xhTf + ((size_t)(rt * 8 + kk) * 64 + lanef) * 8) = h;
    }
  }
}

// Fragment-linear MFMA distance GEMM. Grid 4096 = rowblk(256; 64r) x
// colblk(16; 512c). 8 waves; wave w owns 64r x 64c tile (cols w*64..).
// Every fragment load = one contiguous 1KB burst (perfectly coalesced);
// A-fragments shared by all 8 waves (L1-served); B slice 256KB L2-hot per
// XCD parity. kk ping-pong pipeline; single top-2 epilogue from acc with
// 23-bit-prefix|col9 keys; cross-wave LDS fold -> m1 u32 / m2 u16 per colblk.
__global__ __launch_bounds__(512, 3) void k_gemm(const f16* __restrict__ xhTf,
                                                 const f16* __restrict__ ehTf,
                                                 const float* __restrict__ eev,
                                                 u32* __restrict__ m1,
                                                 u16* __restrict__ m2) {
  __shared__ u32 red1[8][64];
  __shared__ u32 red2[8][64];
  const int tid = threadIdx.x;
  const int lane = tid & 63, w = tid >> 6;
  const int l15 = lane & 15, g = lane >> 4;
  const int colblk = blockIdx.x & 15;
  const int rowblk = (int)blockIdx.x >> 4;

  const f16* pa = xhTf + (size_t)rowblk * 16384 + lane * 8;
  const f16* pb = ehTf + (size_t)(colblk * 32 + w * 4) * 4096 + lane * 8;

  f32x4 acc[4][4];
#pragma unroll
  for (int i = 0; i < 4; ++i)
#pragma unroll
    for (int j = 0; j < 4; ++j) acc[i][j] = (f32x4){0.f, 0.f, 0.f, 0.f};

  half8 af[2][4], bf[2][4];
#pragma unroll
  for (int mt = 0; mt < 4; ++mt) af[0][mt] = *(const half8*)(pa + mt * 4096);
#pragma unroll
  for (int nt = 0; nt < 4; ++nt) bf[0][nt] = *(const half8*)(pb + nt * 4096);

#pragma unroll
  for (int kk = 0; kk < 8; ++kk) {
    const int cur = kk & 1, nxt = cur ^ 1;
    if (kk < 7) {
#pragma unroll
      for (int mt = 0; mt < 4; ++mt)
        af[nxt][mt] = *(const half8*)(pa + mt * 4096 + (kk + 1) * 512);
#pragma unroll
      for (int nt = 0; nt < 4; ++nt)
        bf[nxt][nt] = *(const half8*)(pb + nt * 4096 + (kk + 1) * 512);
    }
#pragma unroll
    for (int mt = 0; mt < 4; ++mt)
#pragma unroll
      for (int nt = 0; nt < 4; ++nt)
        acc[mt][nt] = __builtin_amdgcn_mfma_f32_16x16x32_f16(af[cur][mt], bf[cur][nt], acc[mt][nt], 0, 0, 0);
  }

  // epilogue: keys = float-bits(d16) top-23 | col9 (col-in-colblk)
  float ee16[4];
#pragma unroll
  for (int nt = 0; nt < 4; ++nt)
    ee16[nt] = eev[colblk * 512 + (w * 4 + nt) * 16 + l15] + 16.0f;
#pragma unroll
  for (int mt = 0; mt < 4; ++mt) {
#pragma unroll
    for (int r = 0; r < 4; ++r) {
      u32 s1 = 0xFFFFFFFFu, s2 = 0xFFFFFFFFu;
#pragma unroll
      for (int nt = 0; nt < 4; ++nt) {
        float d16 = fmaf(-2.f, acc[mt][nt][r], ee16[nt]);
        u32 k = (__float_as_uint(d16) & 0xFFFFFE00u) | (u32)((w * 4 + nt) * 16 + l15);
        u32 t = umax32(s1, k);
        s1 = umin32(s1, k);
        s2 = umin32(s2, t);
      }
#pragma unroll
      for (int msk = 1; msk < 16; msk <<= 1) {
        u32 o1 = (u32)__shfl_xor((int)s1, msk, 64);
        u32 o2 = (u32)__shfl_xor((int)s2, msk, 64);
        u32 t = umax32(s1, o1);
        s1 = umin32(s1, o1);
        s2 = umin32(umin32(s2, o2), t);
      }
      if (l15 == 0) {
        int rl = mt * 16 + g * 4 + r;
        red1[w][rl] = s1;
        red2[w][rl] = s2;
      }
    }
  }
  __syncthreads();
  if (tid < 64) {
    u32 k1 = red1[0][tid], k2 = red2[0][tid];
#pragma unroll
    for (int wv = 1; wv < 8; ++wv) {
      u32 a = red1[wv][tid], b2 = red2[wv][tid];
      u32 t = umax32(k1, a);
      k1 = umin32(k1, a);
      k2 = umin32(k2, umin32(t, b2));
    }
    int row = rowblk * 64 + tid;
    m1[(size_t)row * 16 + colblk] = k1;
    float d2 = __uint_as_float(k2 & 0xFFFFFE00u);          // d16-domain lower bound
    float tq = fmaxf(fminf(d2 * 2048.0f, 65535.f), 0.f);   // NaN-safe
    m2[(size_t)row * 16 + colblk] = (u16)(u32)tq;
  }
}

// one wave per row: window test over 16 colblk top1/top2; direct write when
// unambiguous; else exact rescore of in-window top1s + enqueue colblk tasks.
__global__ __launch_bounds__(256) void k_sel(const float* __restrict__ x,
                                             const float* __restrict__ e,
                                             const u32* __restrict__ m1,
                                             const u16* __restrict__ m2,
                                             const float* __restrict__ Fv,
                                             const float* __restrict__ eev,
                                             const u32* __restrict__ eemax,
                                             u64* __restrict__ best,
                                             u32* __restrict__ cnt,
                                             u32* __restrict__ list) {
  const int row = blockIdx.x * 4 + (threadIdx.x >> 6);
  const int lane = threadIdx.x & 63;
  u32 m1v = 0xFFFFFFFFu;
  u32 m2v = 0xFFFFu;
  if (lane < 16) {
    m1v = m1[(size_t)row * 16 + lane];
    m2v = (u32)m2[(size_t)row * 16 + lane];
  }
  u32 gk = m1v;
#pragma unroll
  for (int msk = 1; msk < 64; msk <<= 1) gk = umin32(gk, (u32)__shfl_xor((int)gk, msk, 64));
  const float F = Fv[row];
  const float eps = 0x1p-9f * sqrtf(F * __uint_as_float(*eemax)) + 4e-4f;
  const float thr = (__uint_as_float(gk & 0xFFFFFE00u) - 16.0f) + 2.f * eps + 2e-3f;

  const bool f1 = (lane < 16) && (__uint_as_float(m1v & 0xFFFFFE00u) - 16.0f <= thr);
  const bool trig = (lane < 16) && ((float)m2v * (1.0f / 2048.0f) - 16.0f <= thr);
  const u64 bal = __ballot(f1);
  const bool anyt = __any(trig);

  const int col = lane * 512 + (int)(m1v & 511u);
  const int b = row >> 10, hw = row & 1023;

  if (__popcll(bal) == 1 && !anyt) {
    if (f1) best[row] = (u64)(unsigned)col;        // unambiguous: key 0
  } else {
    if (f1) {
      float d = exact_d(x, e, b, hw, col, F, eev);
      atomicMin(&best[row], pack64(d, (unsigned)col));
    }
    if (trig) {
      u32 slot = atomicAdd(cnt, 1u);
      if (slot < LCAP) list[slot] = (u32)((row << 4) | lane);
      else {   // overflow fallback (correctness only, ~never)
        for (int j = 0; j < 512; ++j) {
          int cj = lane * 512 + j;
          float d = exact_d(x, e, b, hw, cj, F, eev);
          atomicMin(&best[row], pack64(d, (unsigned)cj));
        }
      }
    }
  }
}

// full-colblk (512-col) exact rescore: wave per task, 8 cols/lane
__global__ __launch_bounds__(256) void k_chunk(const float* __restrict__ x,
                                               const float* __restrict__ e,
                                               const float* __restrict__ Fv,
                                               const float* __restrict__ eev,
                                               const u32* __restrict__ cnt,
                                               const u32* __restrict__ list,
                                               u64* __restrict__ best) {
  u32 n = *cnt; if (n > LCAP) n = LCAP;
  const int lane = threadIdx.x & 63;
  for (u32 t = blockIdx.x * 4 + (threadIdx.x >> 6); t < n; t += gridDim.x * 4) {
    u32 v = list[t];
    int row = (int)(v >> 4), cb = (int)(v & 15u);
    int b = row >> 10, hw = row & 1023;
    float F = Fv[row];
    int base = cb * 512 + lane;
    float a[8];
#pragma unroll
    for (int q = 0; q < 8; ++q) a[q] = 0.f;
#pragma unroll 4
    for (int c = 0; c < 256; ++c) {
      float xv = x[((size_t)(b * 256 + c) << 10) + hw];
      const float* ep = e + (size_t)c * KD + base;
#pragma unroll
      for (int q = 0; q < 8; ++q) a[q] = fmaf(xv, ep[q * 64], a[q]);
    }
#pragma unroll
    for (int q = 0; q < 8; ++q) {
      int col = base + q * 64;
      float t2 = fmaf(-2.f, a[q], F);
      float d = t2 + eev[col];
      atomicMin(&best[row], pack64(d, (unsigned)col));
    }
  }
}

// extract idx (u16) + eind + counts
__global__ __launch_bounds__(256) void k_ind(const u64* __restrict__ best,
                                             u16* __restrict__ idx16,
                                             int* __restrict__ counts,
                                             float* __restrict__ out) {
  int n = blockIdx.x * 256 + threadIdx.x;
  u32 idx = (u32)(best[n] & 0xFFFFFFFFull);
  idx16[n] = (u16)idx;
  out[EIND_OFF + n] = (float)idx;
  atomicAdd(&counts[idx], 1);
}

// quantize + straight-through + diff partials (float4-vectorized)
__global__ __launch_bounds__(256) void k_out(const float* __restrict__ x,
                                             const float* __restrict__ e,
                                             const u16* __restrict__ idx16,
                                             float* __restrict__ out,
                                             float* __restrict__ dpart) {
  __shared__ float sd[256];
  int tid = threadIdx.x;
  float local = 0.0f;
  for (size_t v = (size_t)blockIdx.x * 256 + tid; v < 1048576ull; v += 262144ull) {
    size_t i = v * 4;
    int hw = (int)(i & 1023);
    int c = (int)((i >> 10) & 255);
    int bb = (int)(i >> 18);
    int n = (bb << 10) + hw;
    ushort4 id4 = *(const ushort4*)(idx16 + n);
    float4 xv = *(const float4*)(x + i);
    const float* ec = e + (size_t)c * KD;
    float d0 = ec[id4.x] - xv.x;
    float d1 = ec[id4.y] - xv.y;
    float d2 = ec[id4.z] - xv.z;
    float d3 = ec[id4.w] - xv.w;
    float4 o = {xv.x + d0, xv.y + d1, xv.z + d2, xv.w + d3};
    *(float4*)(out + i) = o;
    local += d0 * d0 + d1 * d1 + d2 * d2 + d3 * d3;
  }
  sd[tid] = local;
  __syncthreads();
  for (int s = 128; s > 0; s >>= 1) {
    if (tid < s) sd[tid] += sd[tid + s];
    __syncthreads();
  }
  if (tid == 0) dpart[blockIdx.x] = sd[0];
}

__global__ __launch_bounds__(256) void k_perp(const int* __restrict__ counts,
                                              const float* __restrict__ dpart,
                                              float* __restrict__ out) {
  __shared__ float sd[256];
  int tid = threadIdx.x;
  float s = 0.0f;
  for (int k = tid; k < KD; k += 256) {
    float p = (float)counts[k] * (1.0f / 16384.0f);
    s += p * logf(p + 1e-10f);
  }
  sd[tid] = s;
  __syncthreads();
  for (int t = 128; t > 0; t >>= 1) {
    if (tid < t) sd[tid] += sd[tid + t];
    __syncthreads();
  }
  float S = sd[0];
  __syncthreads();
  float d = 0.0f;
  for (int t = tid; t < 1024; t += 256) d += dpart[t];
  sd[tid] = d;
  __syncthreads();
  for (int t = 128; t > 0; t >>= 1) {
    if (tid < t) sd[tid] += sd[tid + t];
    __syncthreads();
  }
  if (tid == 0) {
    out[DIFF_OFF] = sd[0] * (1.0f / 4194304.0f);
    out[PERP_OFF] = expf(-S);
  }
}

extern "C" void kernel_launch(void* const* d_in, const int* in_sizes, int n_in,
                              void* d_out, int out_size, void* d_ws, size_t ws_size,
                              hipStream_t stream) {
  const float* x = (const float*)d_in[0];   // [16,256,32,32]
  const float* e = (const float*)d_in[1];   // [256,8192]
  float* out = (float*)d_out;
  char* dc = (char*)d_out;
  char* ws = (char*)d_ws;

  u64* best = (u64*)(ws);
  float* Fv = (float*)(ws + 131072);
  float* eev = (float*)(ws + 196608);
  u16* idx16 = (u16*)(ws + 229376);
  int* counts = (int*)(ws + 262144);
  float* dpart = (float*)(ws + 294912);
  u32* eemax = (u32*)(ws + 299008);
  u32* cnt = (u32*)(ws + 299012);

  f16* ehTf = (f16*)(dc);
  f16* xhTf = (f16*)(dc + 4194304);
  u32* m1 = (u32*)(dc + 12582912);
  u16* m2 = (u16*)(dc + 13631488);
  u32* list = (u32*)(dc + 14155776);

  hipMemsetAsync(best, 0xFF, 131072, stream);
  hipMemsetAsync(counts, 0, 36872, stream);   // counts+dpart+eemax+cnt

  k_prep<<<1632, 256, 0, stream>>>(x, e, Fv, eev, eemax, ehTf, xhTf);
  k_gemm<<<4096, 512, 0, stream>>>(xhTf, ehTf, eev, m1, m2);
  k_sel<<<4096, 256, 0, stream>>>(x, e, m1, m2, Fv, eev, eemax, best, cnt, list);
  k_chunk<<<1024, 256, 0, stream>>>(x, e, Fv, eev, cnt, list, best);
  k_ind<<<64, 256, 0, stream>>>(best, idx16, counts, out);
  k_out<<<1024, 256, 0, stream>>>(x, e, idx16, out, dpart);
  k_perp<<<1, 256, 0, stream>>>(counts, dpart, out);
}

// Round 9
// 266.587 us; speedup vs baseline: 1.6653x; 1.2097x over previous
//
#include <hip/hip_runtime.h>

typedef _Float16 f16;
typedef f16 half8 __attribute__((ext_vector_type(8)));
typedef float f32x4 __attribute__((ext_vector_type(4)));
typedef unsigned long long u64;
typedef unsigned int u32;
typedef unsigned short u16;

#define KD 8192
#define DIFF_OFF 4194304
#define EIND_OFF 4194305
#define PERP_OFF 4210689
#define LCAP 262144

// ---- ws layout (bytes), total 299016 (< known-safe 331776) ----
// best u64[16384]@0 | Fv@131072 | eev@196608 | idx16 u16[16384]@229376 |
// counts@262144 | dpart f32[1024]@294912 | eemax@299008 | cnt@299012
// ---- d_out scratch (dead before k_out writes quantize) ----
// ehTf f16 frag-linear [512 tiles][8 kk][64 lane][8] @0      (4MB)
// xhTf f16 frag-linear [1024 tiles][8][64][8]        @4MB    (8MB)
// m1 u32[16384][16] @12582912 (1MB) | m2 u16[16384][16] @13631488 (512KB)
// list u32[LCAP] @14155776 (1MB)

__device__ inline u32 umin32(u32 a, u32 b) { return a < b ? a : b; }
__device__ inline u32 umax32(u32 a, u32 b) { return a > b ? a : b; }
__device__ inline u64 pack64(float d, unsigned col) {
  u32 u = __float_as_uint(d);
  u = (u >> 31) ? ~u : (u | 0x80000000u);
  return ((u64)u << 32) | col;
}
// exact distance chain — bit-identical to rounds 1-8 (validated absmax 0)
__device__ inline float exact_d(const float* __restrict__ x, const float* __restrict__ e,
                                int b, int hw, int col, float F, const float* __restrict__ eev) {
  float a = 0.f;
#pragma unroll 8
  for (int c = 0; c < 256; ++c)
    a = fmaf(x[((size_t)(b * 256 + c) << 10) + hw], e[(size_t)c * KD + col], a);
  float t = fmaf(-2.f, a, F);
  return t + eev[col];
}

// blocks 0..31: ee | 32..95: Fv | 96..607: ehTf | 608..1631: xhTf
__global__ __launch_bounds__(256) void k_prep(const float* __restrict__ x,
                                              const float* __restrict__ e,
                                              float* __restrict__ Fv,
                                              float* __restrict__ eev,
                                              u32* __restrict__ eemax,
                                              f16* __restrict__ ehTf,
                                              f16* __restrict__ xhTf) {
#pragma clang fp contract(off)
  __shared__ float sm[64][65];
  const int bid = blockIdx.x, tid = threadIdx.x;
  if (bid < 32) {              // ||e_k||^2, np sequential order (validated)
    int k = bid * 256 + tid;
    float s = 0.0f;
    for (int c = 0; c < 256; ++c) { float v = e[(size_t)c * KD + k]; float sq = v * v; s = s + sq; }
    eev[k] = s;
    atomicMax(eemax, __float_as_uint(s));
  } else if (bid < 96) {       // ||f_n||^2, numpy pairwise (validated)
    int n = (bid - 32) * 256 + tid;
    int b = n >> 10, hw = n & 1023;
    const float* px = x + ((size_t)b << 18) + hw;
    float sblk[2];
#pragma unroll
    for (int blk = 0; blk < 2; ++blk) {
      float r[8];
#pragma unroll
      for (int j = 0; j < 8; ++j) { float v = px[(size_t)(blk * 128 + j) << 10]; r[j] = v * v; }
      for (int i = 8; i < 128; i += 8) {
#pragma unroll
        for (int j = 0; j < 8; ++j) {
          float v = px[(size_t)(blk * 128 + i + j) << 10];
          float sq = v * v;
          r[j] = r[j] + sq;
        }
      }
      sblk[blk] = ((r[0] + r[1]) + (r[2] + r[3])) + ((r[4] + r[5]) + (r[6] + r[7]));
    }
    Fv[n] = sblk[0] + sblk[1];
  } else if (bid < 608) {      // ehTf fragment-linear from e[c][k]
    int t = bid - 96;
    int k0 = (t >> 2) * 64, c0 = (t & 3) * 64;
    int tx = tid & 63, ty = tid >> 6;
#pragma unroll
    for (int i = 0; i < 16; ++i) {
      int cl = i * 4 + ty;
      sm[cl][tx] = e[(size_t)(c0 + cl) * KD + k0 + tx];
    }
    __syncthreads();
#pragma unroll
    for (int p = 0; p < 2; ++p) {
      int i = tid + p * 256;
      int kl = i & 63, cg = i >> 6;
      int kkl = cg >> 2, gg = cg & 3;
      int chb = kkl * 32 + gg * 8;
      half8 h;
#pragma unroll
      for (int j = 0; j < 8; ++j) h[j] = (f16)sm[chb + j][kl];
      int tile = (k0 >> 4) + (kl >> 4);
      int kk = (c0 >> 5) + kkl;
      int lanef = gg * 16 + (kl & 15);
      *(half8*)(ehTf + ((size_t)(tile * 8 + kk) * 64 + lanef) * 8) = h;
    }
  } else {                     // xhTf fragment-linear from x[b][c][hw]
    int t = bid - 608;
    int b = t >> 6, rem = t & 63;
    int hw0 = (rem >> 2) * 64, c0 = (rem & 3) * 64;
    int tx = tid & 63, ty = tid >> 6;
#pragma unroll
    for (int i = 0; i < 16; ++i) {
      int cl = i * 4 + ty;
      sm[cl][tx] = x[((size_t)(b * 256 + c0 + cl) << 10) + hw0 + tx];
    }
    __syncthreads();
#pragma unroll
    for (int p = 0; p < 2; ++p) {
      int i = tid + p * 256;
      int nl = i & 63, cg = i >> 6;
      int kkl = cg >> 2, gg = cg & 3;
      int chb = kkl * 32 + gg * 8;
      half8 h;
#pragma unroll
      for (int j = 0; j < 8; ++j) h[j] = (f16)sm[chb + j][nl];
      int rt = b * 64 + (hw0 >> 4) + (nl >> 4);
      int kk = (c0 >> 5) + kkl;
      int lanef = gg * 16 + (nl & 15);
      *(half8*)(xhTf + ((size_t)(rt * 8 + kk) * 64 + lanef) * 8) = h;
    }
  }
}

// Fragment-linear MFMA distance GEMM. Grid 2048 = rowblk(128; 128r) x
// colblk(16; 512c). 8 waves 2x4: wave-tile 64r x 128c (acc[4][8]).
// Fragment loads = contiguous 1KB bursts; cross-wave duplicates (A x4 among
// same-wm, B x2 among same-wn) are same-address -> L1-broadcast. Unique L2
// per WG = 320KB per 4.1us => 77 GB/s/CU, under the 134 GB/s L2 share.
// kk ping-pong; top-2 epilogue with 23-bit-prefix|col9 keys; cross-wave
// LDS fold -> m1 u32 / m2 u16 per (row, colblk).
__global__ __launch_bounds__(512, 2) void k_gemm(const f16* __restrict__ xhTf,
                                                 const f16* __restrict__ ehTf,
                                                 const float* __restrict__ eev,
                                                 u32* __restrict__ m1,
                                                 u16* __restrict__ m2) {
  __shared__ u32 red1[4][128];
  __shared__ u32 red2[4][128];
  const int tid = threadIdx.x;
  const int lane = tid & 63, w = tid >> 6;
  const int wm = w >> 2, wn = w & 3;
  const int l15 = lane & 15, g = lane >> 4;
  const int colblk = blockIdx.x & 15;
  const int rowblk = (int)blockIdx.x >> 4;

  // A row-tiles rowblk*8 + wm*4 + mt; B col-tiles colblk*32 + wn*8 + nt
  const f16* pa = xhTf + (size_t)(rowblk * 8 + wm * 4) * 4096 + lane * 8;
  const f16* pb = ehTf + (size_t)(colblk * 32 + wn * 8) * 4096 + lane * 8;

  f32x4 acc[4][8];
#pragma unroll
  for (int i = 0; i < 4; ++i)
#pragma unroll
    for (int j = 0; j < 8; ++j) acc[i][j] = (f32x4){0.f, 0.f, 0.f, 0.f};

  half8 af[2][4], bf[2][8];
#pragma unroll
  for (int mt = 0; mt < 4; ++mt) af[0][mt] = *(const half8*)(pa + mt * 4096);
#pragma unroll
  for (int nt = 0; nt < 8; ++nt) bf[0][nt] = *(const half8*)(pb + nt * 4096);

#pragma unroll
  for (int kk = 0; kk < 8; ++kk) {
    const int cur = kk & 1, nxt = cur ^ 1;
    if (kk < 7) {
#pragma unroll
      for (int mt = 0; mt < 4; ++mt)
        af[nxt][mt] = *(const half8*)(pa + mt * 4096 + (kk + 1) * 512);
#pragma unroll
      for (int nt = 0; nt < 8; ++nt)
        bf[nxt][nt] = *(const half8*)(pb + nt * 4096 + (kk + 1) * 512);
    }
#pragma unroll
    for (int mt = 0; mt < 4; ++mt)
#pragma unroll
      for (int nt = 0; nt < 8; ++nt)
        acc[mt][nt] = __builtin_amdgcn_mfma_f32_16x16x32_f16(af[cur][mt], bf[cur][nt], acc[mt][nt], 0, 0, 0);
  }

  // epilogue: keys = float-bits(d16) top-23 | col9 (col-in-colblk)
  float ee16[8];
#pragma unroll
  for (int nt = 0; nt < 8; ++nt)
    ee16[nt] = eev[colblk * 512 + wn * 128 + nt * 16 + l15] + 16.0f;
#pragma unroll
  for (int mt = 0; mt < 4; ++mt) {
#pragma unroll
    for (int r = 0; r < 4; ++r) {
      u32 s1 = 0xFFFFFFFFu, s2 = 0xFFFFFFFFu;
#pragma unroll
      for (int nt = 0; nt < 8; ++nt) {
        float d16 = fmaf(-2.f, acc[mt][nt][r], ee16[nt]);
        u32 k = (__float_as_uint(d16) & 0xFFFFFE00u) | (u32)(wn * 128 + nt * 16 + l15);
        u32 t = umax32(s1, k);
        s1 = umin32(s1, k);
        s2 = umin32(s2, t);
      }
#pragma unroll
      for (int msk = 1; msk < 16; msk <<= 1) {
        u32 o1 = (u32)__shfl_xor((int)s1, msk, 64);
        u32 o2 = (u32)__shfl_xor((int)s2, msk, 64);
        u32 t = umax32(s1, o1);
        s1 = umin32(s1, o1);
        s2 = umin32(umin32(s2, o2), t);
      }
      if (l15 == 0) {
        int rl = wm * 64 + mt * 16 + g * 4 + r;
        red1[wn][rl] = s1;
        red2[wn][rl] = s2;
      }
    }
  }
  __syncthreads();
  if (tid < 128) {
    u32 k1 = red1[0][tid], k2 = red2[0][tid];
#pragma unroll
    for (int wv = 1; wv < 4; ++wv) {
      u32 a = red1[wv][tid], b2 = red2[wv][tid];
      u32 t = umax32(k1, a);
      k1 = umin32(k1, a);
      k2 = umin32(k2, umin32(t, b2));
    }
    int row = rowblk * 128 + tid;
    m1[(size_t)row * 16 + colblk] = k1;
    float d2 = __uint_as_float(k2 & 0xFFFFFE00u);          // d16-domain lower bound
    float tq = fmaxf(fminf(d2 * 2048.0f, 65535.f), 0.f);   // NaN-safe
    m2[(size_t)row * 16 + colblk] = (u16)(u32)tq;
  }
}

// one wave per row: window test over 16 colblk top1/top2; direct write when
// unambiguous; else exact rescore of in-window top1s + enqueue colblk tasks.
__global__ __launch_bounds__(256) void k_sel(const float* __restrict__ x,
                                             const float* __restrict__ e,
                                             const u32* __restrict__ m1,
                                             const u16* __restrict__ m2,
                                             const float* __restrict__ Fv,
                                             const float* __restrict__ eev,
                                             const u32* __restrict__ eemax,
                                             u64* __restrict__ best,
                                             u32* __restrict__ cnt,
                                             u32* __restrict__ list) {
  const int row = blockIdx.x * 4 + (threadIdx.x >> 6);
  const int lane = threadIdx.x & 63;
  u32 m1v = 0xFFFFFFFFu;
  u32 m2v = 0xFFFFu;
  if (lane < 16) {
    m1v = m1[(size_t)row * 16 + lane];
    m2v = (u32)m2[(size_t)row * 16 + lane];
  }
  u32 gk = m1v;
#pragma unroll
  for (int msk = 1; msk < 64; msk <<= 1) gk = umin32(gk, (u32)__shfl_xor((int)gk, msk, 64));
  const float F = Fv[row];
  const float eps = 0x1p-9f * sqrtf(F * __uint_as_float(*eemax)) + 4e-4f;
  const float thr = (__uint_as_float(gk & 0xFFFFFE00u) - 16.0f) + 2.f * eps + 2e-3f;

  const bool f1 = (lane < 16) && (__uint_as_float(m1v & 0xFFFFFE00u) - 16.0f <= thr);
  const bool trig = (lane < 16) && ((float)m2v * (1.0f / 2048.0f) - 16.0f <= thr);
  const u64 bal = __ballot(f1);
  const bool anyt = __any(trig);

  const int col = lane * 512 + (int)(m1v & 511u);
  const int b = row >> 10, hw = row & 1023;

  if (__popcll(bal) == 1 && !anyt) {
    if (f1) best[row] = (u64)(unsigned)col;        // unambiguous: key 0
  } else {
    if (f1) {
      float d = exact_d(x, e, b, hw, col, F, eev);
      atomicMin(&best[row], pack64(d, (unsigned)col));
    }
    if (trig) {
      u32 slot = atomicAdd(cnt, 1u);
      if (slot < LCAP) list[slot] = (u32)((row << 4) | lane);
      else {   // overflow fallback (correctness only, ~never)
        for (int j = 0; j < 512; ++j) {
          int cj = lane * 512 + j;
          float d = exact_d(x, e, b, hw, cj, F, eev);
          atomicMin(&best[row], pack64(d, (unsigned)cj));
        }
      }
    }
  }
}

// full-colblk (512-col) exact rescore: wave per task, 8 cols/lane
__global__ __launch_bounds__(256) void k_chunk(const float* __restrict__ x,
                                               const float* __restrict__ e,
                                               const float* __restrict__ Fv,
                                               const float* __restrict__ eev,
                                               const u32* __restrict__ cnt,
                                               const u32* __restrict__ list,
                                               u64* __restrict__ best) {
  u32 n = *cnt; if (n > LCAP) n = LCAP;
  const int lane = threadIdx.x & 63;
  for (u32 t = blockIdx.x * 4 + (threadIdx.x >> 6); t < n; t += gridDim.x * 4) {
    u32 v = list[t];
    int row = (int)(v >> 4), cb = (int)(v & 15u);
    int b = row >> 10, hw = row & 1023;
    float F = Fv[row];
    int base = cb * 512 + lane;
    float a[8];
#pragma unroll
    for (int q = 0; q < 8; ++q) a[q] = 0.f;
#pragma unroll 4
    for (int c = 0; c < 256; ++c) {
      float xv = x[((size_t)(b * 256 + c) << 10) + hw];
      const float* ep = e + (size_t)c * KD + base;
#pragma unroll
      for (int q = 0; q < 8; ++q) a[q] = fmaf(xv, ep[q * 64], a[q]);
    }
#pragma unroll
    for (int q = 0; q < 8; ++q) {
      int col = base + q * 64;
      float t2 = fmaf(-2.f, a[q], F);
      float d = t2 + eev[col];
      atomicMin(&best[row], pack64(d, (unsigned)col));
    }
  }
}

// extract idx (u16) + eind + counts
__global__ __launch_bounds__(256) void k_ind(const u64* __restrict__ best,
                                             u16* __restrict__ idx16,
                                             int* __restrict__ counts,
                                             float* __restrict__ out) {
  int n = blockIdx.x * 256 + threadIdx.x;
  u32 idx = (u32)(best[n] & 0xFFFFFFFFull);
  idx16[n] = (u16)idx;
  out[EIND_OFF + n] = (float)idx;
  atomicAdd(&counts[idx], 1);
}

// quantize + straight-through + diff partials (float4-vectorized)
__global__ __launch_bounds__(256) void k_out(const float* __restrict__ x,
                                             const float* __restrict__ e,
                                             const u16* __restrict__ idx16,
                                             float* __restrict__ out,
                                             float* __restrict__ dpart) {
  __shared__ float sd[256];
  int tid = threadIdx.x;
  float local = 0.0f;
  for (size_t v = (size_t)blockIdx.x * 256 + tid; v < 1048576ull; v += 262144ull) {
    size_t i = v * 4;
    int hw = (int)(i & 1023);
    int c = (int)((i >> 10) & 255);
    int bb = (int)(i >> 18);
    int n = (bb << 10) + hw;
    ushort4 id4 = *(const ushort4*)(idx16 + n);
    float4 xv = *(const float4*)(x + i);
    const float* ec = e + (size_t)c * KD;
    float d0 = ec[id4.x] - xv.x;
    float d1 = ec[id4.y] - xv.y;
    float d2 = ec[id4.z] - xv.z;
    float d3 = ec[id4.w] - xv.w;
    float4 o = {xv.x + d0, xv.y + d1, xv.z + d2, xv.w + d3};
    *(float4*)(out + i) = o;
    local += d0 * d0 + d1 * d1 + d2 * d2 + d3 * d3;
  }
  sd[tid] = local;
  __syncthreads();
  for (int s = 128; s > 0; s >>= 1) {
    if (tid < s) sd[tid] += sd[tid + s];
    __syncthreads();
  }
  if (tid == 0) dpart[blockIdx.x] = sd[0];
}

__global__ __launch_bounds__(256) void k_perp(const int* __restrict__ counts,
                                              const float* __restrict__ dpart,
                                              float* __restrict__ out) {
  __shared__ float sd[256];
  int tid = threadIdx.x;
  float s = 0.0f;
  for (int k = tid; k < KD; k += 256) {
    float p = (float)counts[k] * (1.0f / 16384.0f);
    s += p * logf(p + 1e-10f);
  }
  sd[tid] = s;
  __syncthreads();
  for (int t = 128; t > 0; t >>= 1) {
    if (tid < t) sd[tid] += sd[tid + t];
    __syncthreads();
  }
  float S = sd[0];
  __syncthreads();
  float d = 0.0f;
  for (int t = tid; t < 1024; t += 256) d += dpart[t];
  sd[tid] = d;
  __syncthreads();
  for (int t = 128; t > 0; t >>= 1) {
    if (tid < t) sd[tid] += sd[tid + t];
    __syncthreads();
  }
  if (tid == 0) {
    out[DIFF_OFF] = sd[0] * (1.0f / 4194304.0f);
    out[PERP_OFF] = expf(-S);
  }
}

extern "C" void kernel_launch(void* const* d_in, const int* in_sizes, int n_in,
                              void* d_out, int out_size, void* d_ws, size_t ws_size,
                              hipStream_t stream) {
  const float* x = (const float*)d_in[0];   // [16,256,32,32]
  const float* e = (const float*)d_in[1];   // [256,8192]
  float* out = (float*)d_out;
  char* dc = (char*)d_out;
  char* ws = (char*)d_ws;

  u64* best = (u64*)(ws);
  float* Fv = (float*)(ws + 131072);
  float* eev = (float*)(ws + 196608);
  u16* idx16 = (u16*)(ws + 229376);
  int* counts = (int*)(ws + 262144);
  float* dpart = (float*)(ws + 294912);
  u32* eemax = (u32*)(ws + 299008);
  u32* cnt = (u32*)(ws + 299012);

  f16* ehTf = (f16*)(dc);
  f16* xhTf = (f16*)(dc + 4194304);
  u32* m1 = (u32*)(dc + 12582912);
  u16* m2 = (u16*)(dc + 13631488);
  u32* list = (u32*)(dc + 14155776);

  hipMemsetAsync(best, 0xFF, 131072, stream);
  hipMemsetAsync(counts, 0, 36872, stream);   // counts+dpart+eemax+cnt

  k_prep<<<1632, 256, 0, stream>>>(x, e, Fv, eev, eemax, ehTf, xhTf);
  k_gemm<<<2048, 512, 0, stream>>>(xhTf, ehTf, eev, m1, m2);
  k_sel<<<4096, 256, 0, stream>>>(x, e, m1, m2, Fv, eev, eemax, best, cnt, list);
  k_chunk<<<1024, 256, 0, stream>>>(x, e, Fv, eev, cnt, list, best);
  k_ind<<<64, 256, 0, stream>>>(best, idx16, counts, out);
  k_out<<<1024, 256, 0, stream>>>(x, e, idx16, out, dpart);
  k_perp<<<1, 256, 0, stream>>>(counts, dpart, out);
}